// Round 11
// baseline (5673.034 us; speedup 1.0000x reference)
//
#include <hip/hip_runtime.h>
#include <hip/hip_bf16.h>
#include <math.h>

typedef __attribute__((ext_vector_type(8))) short bf16x8;
typedef __attribute__((ext_vector_type(4))) float f32x4;

static constexpr int Tc = 512, HIDc = 512;
static constexpr int NWGc = 256, THR = 256;

// ws byte offsets. Slabs are bf16 [64 batch][512 k] = 64 KB each.
static constexpr size_t WSB_H0  = 0;                      // [8] h0(t) at t&7
static constexpr size_t WSB_H1  = WSB_H0 + 8ull * 65536;  // [4] h1(t) at t&3
static constexpr size_t WSB_XE  = WSB_H1 + 4ull * 65536;  // [4] emb(t) at t&3
// counter block (contiguous, zeroed by wg0 at init): arrivals 8x16u32,
// h0-ready 8 slots x 4 stripes x 16u32, h1-ready same.
static constexpr size_t WSB_CTR = WSB_XE + 4ull * 65536;  // 4608 B
static constexpr size_t WSB_EPO = WSB_CTR + 4608;         // epoch, own line
static constexpr size_t WSB_FLG = WSB_EPO + 64;           // 256 flags, 64B apart
static constexpr size_t WSB_END = WSB_FLG + 256 * 64;

static constexpr unsigned FMAGIC = 0x1357acedu;
static constexpr unsigned EPBASE = 0x40000000u;
static constexpr int SPIN_CAP = 1 << 20;   // fail fast, never hang

__device__ __forceinline__ unsigned ld_devu(const unsigned* p) {
    return __hip_atomic_load(p, __ATOMIC_RELAXED, __HIP_MEMORY_SCOPE_AGENT);
}
__device__ __forceinline__ unsigned long long ld_devu64(const unsigned long long* p) {
    return __hip_atomic_load(p, __ATOMIC_RELAXED, __HIP_MEMORY_SCOPE_AGENT);
}
__device__ __forceinline__ void st_devu(unsigned* p, unsigned v) {
    __hip_atomic_store(p, v, __ATOMIC_RELAXED, __HIP_MEMORY_SCOPE_AGENT);
}
template<int N> __device__ __forceinline__ void s_wait_vm() {
    asm volatile("s_waitcnt vmcnt(%0)" :: "n"(N) : "memory");
}
__device__ __forceinline__ void s_wait_lgkm() {
    asm volatile("s_waitcnt lgkmcnt(0)" ::: "memory");
}
__device__ __forceinline__ void wgbar() {
    asm volatile("" ::: "memory");
    __builtin_amdgcn_s_barrier();
    asm volatile("" ::: "memory");
}
__device__ __forceinline__ unsigned short bfc(float f) {
    __hip_bfloat16 h = __float2bfloat16(f);
    return *(unsigned short*)&h;
}
__device__ __forceinline__ float bf2f(unsigned short u) {
    __hip_bfloat16 h; *(unsigned short*)&h = u;
    return __bfloat162float(h);
}

__global__ __launch_bounds__(THR, 1)
void lstm_persistent(const int* __restrict__ xp,
                     const float* __restrict__ emb,
                     const float* __restrict__ W0,
                     const float* __restrict__ b0,
                     const float* __restrict__ W1,
                     const float* __restrict__ b1,
                     const float* __restrict__ fcw,
                     const float* __restrict__ fcb,
                     float* __restrict__ out,
                     float* __restrict__ ws)
{
    char* wsc = (char*)ws;

    unsigned* ctrU = (unsigned*)(wsc + WSB_CTR);  // [0..127] arrivals
    unsigned* h0c  = ctrU + 128;                  // [8][4][16]
    unsigned* h1c  = ctrU + 128 + 512;            // [8][4][16]
    unsigned* epo  = (unsigned*)(wsc + WSB_EPO);
    unsigned* flg  = (unsigned*)(wsc + WSB_FLG);

    __shared__ float preF[16 * 68];   // gate preacts [w-row][batch]
    __shared__ float hexF[4 * 64];    // h exchange [h_local][batch]

    const int  tid   = threadIdx.x;
    const int  wg    = blockIdx.x;
    const bool is_l0 = (wg < 128);
    const int  hw    = (is_l0 ? wg : wg - 128) * 4;
    const float* Wb  = is_l0 ? W0 : W1;
    const float* bb  = is_l0 ? b0 : b1;
    const int  b_    = tid & 63;
    const int  wv    = __builtin_amdgcn_readfirstlane(tid >> 6);
    // MFMA lane decomposition (16x16x32): n = lane&15, q = lane>>4
    const int  n = tid & 15;
    const int  q = (tid & 63) >> 4;
    const size_t rowB = (size_t)(wv * 16 + n) * 1024 + (size_t)q * 16;

    // ---- diagnostic sentinel (overwritten by the real FC) ----
    if (wg == 0 && tid < 64) out[tid] = 0.25f;

    // ---- init: zero all 12 h slabs (h0[8] + h1[4], contiguous) ----
    {
        unsigned long long* hz = (unsigned long long*)(wsc + WSB_H0);
        for (int i = wg * THR + tid; i < 12 * 8192; i += NWGc * THR)
            __hip_atomic_store(hz + i, 0ull, __ATOMIC_RELAXED, __HIP_MEMORY_SCOPE_AGENT);
    }

    // ---- emb production (l0 WGs; 2 WGs per batch row; waves 2-3) ----
    const int be = wg >> 1;
    const int p2 = ((wg & 1) << 7) + (tid & 127);  // pair index when tid>=128
    auto emb_gather = [&](int wn) -> float2 {
        float2 v = make_float2(0.f, 0.f);
        if (tid >= 128) {
            const int tok = xp[be * Tc + wn];
            if (tok) v = *(const float2*)(emb + (size_t)tok * 512 + p2 * 2);
        }
        return v;
    };
    auto emb_store = [&](int wn, float2 v) {
        if (tid >= 128) {
            unsigned u = (unsigned)bfc(v.x) | ((unsigned)bfc(v.y) << 16);
            st_devu((unsigned*)(wsc + WSB_XE + (size_t)(wn & 3) * 65536) + be * 256 + p2, u);
        }
    };
    if (is_l0) { emb_store(0, emb_gather(0)); emb_store(1, emb_gather(1)); }

    // ---- B-fragments: wave's 16 weight rows, bf16, resident in VGPRs ----
    bf16x8 bw[32];
    {
        const float* wrow = Wb + (size_t)((n >> 2) * HIDc + hw + (n & 3)) * 1024;
        #pragma unroll
        for (int f = 0; f < 32; ++f) {
            const int k0 = f * 32 + q * 8;
            const float4 u0 = *(const float4*)(wrow + k0);
            const float4 u1 = *(const float4*)(wrow + k0 + 4);
            union { unsigned short us[8]; bf16x8 v; } pk;
            pk.us[0] = bfc(u0.x); pk.us[1] = bfc(u0.y);
            pk.us[2] = bfc(u0.z); pk.us[3] = bfc(u0.w);
            pk.us[4] = bfc(u1.x); pk.us[5] = bfc(u1.y);
            pk.us[6] = bfc(u1.z); pk.us[7] = bfc(u1.w);
            bw[f] = pk.v;
        }
    }
    const float bias_n = bb[(n >> 2) * HIDc + hw + (n & 3)];

    // ---- init barrier: flags -> wg0 zeroes counter block -> publishes ----
    s_wait_vm<0>();
    wgbar();
    if (tid == 0) st_devu(&flg[wg * 16], FMAGIC);
    if (wg == 0) {
        if (tid == 0) {
            for (int g = 0; g < NWGc; ++g) {
                int gu = 0;
                while (ld_devu(&flg[g * 16]) != FMAGIC && ++gu < SPIN_CAP)
                    __builtin_amdgcn_s_sleep(1);
            }
        }
        wgbar();
        for (int i = tid; i < 1152; i += THR) st_devu(&ctrU[i], 0u);  // arrivals+h0c+h1c
        s_wait_vm<0>();
        wgbar();
        if (tid == 0) st_devu(epo, EPBASE);
    } else {
        int gu = 0;
        while (ld_devu(epo) != EPBASE && ++gu < SPIN_CAP)
            __builtin_amdgcn_s_sleep(2);
    }
    wgbar();

    float cpriv = 0.0f;

    auto ldfrag = [&](const char* slab, int cloc, int s) -> bf16x8 {
        const unsigned long long* p =
            (const unsigned long long*)(slab + rowB + (size_t)cloc * 256 + (size_t)s * 64);
        union { unsigned long long u[2]; bf16x8 v; } r;
        r.u[0] = ld_devu64(p);
        r.u[1] = ld_devu64(p + 1);
        return r.v;
    };
    // all-lane spin: h-slab for step s ready (128 producer adds, 4 stripes)
    auto spin_ready = [&](const unsigned* baseU, int s) {
        const unsigned tgt = 128u * (unsigned)((s >> 3) + 1);
        const unsigned* p = baseU + (size_t)(s & 7) * 64;
        int gu = 0;
        while ((ld_devu(p) + ld_devu(p + 16) + ld_devu(p + 32) + ld_devu(p + 48)) < tgt
               && ++gu < SPIN_CAP)
            __builtin_amdgcn_s_sleep(1);
    };

    #pragma unroll 1
    for (int w = 0; w <= Tc + 1; ++w) {
        const bool a0  = is_l0 && (w < Tc);     // layer0 computes t=w
        const bool a1  = !is_l0 && (w >= 2);    // layer1 computes t=w-2
        const bool act = a0 || a1;

        // ---- lag-2 epoch gate (consumption safety; 2-step slack) ----
        if (w >= 2) {
            const unsigned etgt = EPBASE + 1u + (unsigned)(w - 2);
            if (wg == 0) {
                if (tid == 0) {
                    const unsigned atgt = 256u * (unsigned)(w - 1);
                    int gu = 0;
                    for (;;) {
                        unsigned s = 0;
                        #pragma unroll
                        for (int g = 0; g < 8; ++g) s += ld_devu(&ctrU[g * 16]);
                        if (s >= atgt || ++gu >= SPIN_CAP) break;
                        __builtin_amdgcn_s_sleep(1);
                    }
                    st_devu(epo, etgt);
                }
                wgbar();
            } else {
                int gu = 0;
                while (ld_devu(epo) < etgt && ++gu < SPIN_CAP)
                    __builtin_amdgcn_s_sleep(2);
            }
        }

        f32x4 acc = {0.f, 0.f, 0.f, 0.f};

        // ---- A-half: l0 = emb(w) [epoch-safe]; l1 = h0(w-2) [ready-gated] ----
        if (act) {
            if (a1) spin_ready(h0c, w - 2);
            const char* slabA = is_l0
                ? (wsc + WSB_XE + (size_t)(w & 3) * 65536)
                : (wsc + WSB_H0 + (size_t)((w - 2) & 7) * 65536);
            bf16x8 fa[16];
            #pragma unroll
            for (int c = 0; c < 4; ++c) {
                #pragma unroll
                for (int s = 0; s < 4; ++s)
                    fa[c * 4 + s] = ldfrag(slabA, c, s);
            }
            #pragma unroll
            for (int i = 0; i < 16; ++i)
                acc = __builtin_amdgcn_mfma_f32_16x16x32_bf16(fa[i], bw[i], acc, 0, 0, 0);
        }

        // ---- emb gather for w+2 (l0 waves 2-3; read-only sources) ----
        const bool ep = is_l0 && (w + 2) < Tc;
        float2 ev = make_float2(0.f, 0.f);
        if (ep) ev = emb_gather(w + 2);

        if (act) {
            // ---- B-half ready gate: ONE counter hop (the critical sync) ----
            if (a0) { if (w >= 1) spin_ready(h0c, w - 1); }
            else    { if (w >= 3) spin_ready(h1c, w - 3); }

            const char* slabB = is_l0
                ? (wsc + WSB_H0 + (size_t)((w - 1) & 7) * 65536)      // h0(w-1)
                : (wsc + WSB_H1 + (size_t)((w - 3) & 3) * 65536);     // h1(w-3)
            bf16x8 fb[16];
            #pragma unroll
            for (int c = 0; c < 4; ++c) {
                #pragma unroll
                for (int s = 0; s < 4; ++s)
                    fb[c * 4 + s] = ldfrag(slabB, c, s);
            }
            #pragma unroll
            for (int i = 0; i < 16; ++i)
                acc = __builtin_amdgcn_mfma_f32_16x16x32_bf16(fb[i], bw[16 + i], acc, 0, 0, 0);

            // ---- gate exchange ----
            *(f32x4*)(preF + (size_t)n * 68 + wv * 16 + q * 4) = acc + bias_n;
            s_wait_lgkm(); wgbar();

            const float pI = preF[(0 * 4 + wv) * 68 + b_];
            const float pF = preF[(1 * 4 + wv) * 68 + b_];
            const float pO = preF[(2 * 4 + wv) * 68 + b_];
            const float pG = preF[(3 * 4 + wv) * 68 + b_];
            const float ig = 1.f / (1.f + expf(-pI));
            const float fg = 1.f / (1.f + expf(-pF));
            const float og = 1.f / (1.f + expf(-pO));
            const float gg = fmaxf(pG, 0.f);
            cpriv = fg * cpriv + ig * gg;
            const float hn = og * fmaxf(cpriv, 0.f);
            hexF[wv * 64 + b_] = hn;
            s_wait_lgkm(); wgbar();

            // ---- wave 0: h-store, wave-local drain, ready-add (release) ----
            if (tid < 64) {
                unsigned long long pk = 0;
                #pragma unroll
                for (int jj = 0; jj < 4; ++jj)
                    pk |= (unsigned long long)bfc(hexF[jj * 64 + tid]) << (16 * jj);
                unsigned short* hdst = is_l0
                    ? (unsigned short*)(wsc + WSB_H0 + (size_t)(w & 7) * 65536)
                    : (unsigned short*)(wsc + WSB_H1 + (size_t)((w - 2) & 3) * 65536);
                __hip_atomic_store((unsigned long long*)(hdst + (size_t)tid * 512 + hw),
                                   pk, __ATOMIC_RELAXED, __HIP_MEMORY_SCOPE_AGENT);
                s_wait_vm<0>();   // wave-0 scope: h-store acked at coherent point
                if (tid == 0) {
                    unsigned* rc = (is_l0 ? h0c : h1c)
                        + (size_t)((is_l0 ? w : (w - 2)) & 7) * 64 + (size_t)(wg & 3) * 16;
                    __hip_atomic_fetch_add(rc, 1u, __ATOMIC_RELAXED,
                                           __HIP_MEMORY_SCOPE_AGENT);
                }
            }
        }

        // ---- emb store for w+2 (waves 2-3) ----
        if (ep) emb_store(w + 2, ev);

        // ---- arrival (feeds the lag-2 epoch barrier) ----
        s_wait_vm<0>();
        wgbar();
        if (tid == 0)
            __hip_atomic_fetch_add(&ctrU[(wg & 7) * 16], 1u, __ATOMIC_RELAXED,
                                   __HIP_MEMORY_SCOPE_AGENT);
    }

    // ---- clear own init flag (replay-safe init barrier) ----
    if (tid == 0) st_devu(&flg[wg * 16], 0u);

    // ---- final FC + sigmoid on h1(Tc-1) ----
    if (wg == 0) {
        if (tid == 0) {
            const unsigned tgt = 256u * (unsigned)(Tc + 2);
            int gu = 0;
            for (;;) {
                unsigned s = 0;
                #pragma unroll
                for (int g = 0; g < 8; ++g) s += ld_devu(&ctrU[g * 16]);
                if (s >= tgt || ++gu >= SPIN_CAP) break;
                __builtin_amdgcn_s_sleep(1);
            }
        }
        wgbar();
        if (tid < 64) {
            const unsigned short* h1f =
                (const unsigned short*)(wsc + WSB_H1 + (size_t)((Tc - 1) & 3) * 65536)
                + (size_t)tid * 512;
            float s = fcb[0];
            for (int h = 0; h < HIDc; h += 4) {
                const unsigned long long u = ld_devu64((const unsigned long long*)(h1f + h));
                s = fmaf(bf2f((unsigned short)(u        & 0xffff)), fcw[h + 0], s);
                s = fmaf(bf2f((unsigned short)((u >> 16) & 0xffff)), fcw[h + 1], s);
                s = fmaf(bf2f((unsigned short)((u >> 32) & 0xffff)), fcw[h + 2], s);
                s = fmaf(bf2f((unsigned short)((u >> 48) & 0xffff)), fcw[h + 3], s);
            }
            out[tid] = 1.f / (1.f + expf(-s));
        }
    }
}

extern "C" void kernel_launch(void* const* d_in, const int* in_sizes, int n_in,
                              void* d_out, int out_size, void* d_ws, size_t ws_size,
                              hipStream_t stream) {
    const int*   xp  = (const int*)d_in[0];
    const float* emb = (const float*)d_in[1];
    const float* W0  = (const float*)d_in[2];
    const float* b0  = (const float*)d_in[3];
    const float* W1  = (const float*)d_in[4];
    const float* b1  = (const float*)d_in[5];
    const float* fcw = (const float*)d_in[6];
    const float* fcb = (const float*)d_in[7];
    float* out = (float*)d_out;
    float* ws  = (float*)d_ws;

    if (ws_size < WSB_END) return;  // loud fail: out stays poisoned

    lstm_persistent<<<dim3(NWGc), dim3(THR), 0, stream>>>(
        xp, emb, W0, b0, W1, b1, fcw, fcb, out, ws);
}

// Round 12
// 4981.913 us; speedup vs baseline: 1.1387x; 1.1387x over previous
//
#include <hip/hip_runtime.h>
#include <hip/hip_bf16.h>
#include <math.h>

typedef __attribute__((ext_vector_type(8))) short bf16x8;
typedef __attribute__((ext_vector_type(4))) float f32x4;

static constexpr int Tc = 512, HIDc = 512;
static constexpr int NWGc = 256, THR = 256;

// ws byte offsets. Slabs are bf16 [64 batch][512 k] = 64 KB each.
static constexpr size_t WSB_H0  = 0;                     // [3] h0(t) at t%3
static constexpr size_t WSB_H1  = WSB_H0 + 3ull * 65536; // [2] h1(t) at t&1
static constexpr size_t WSB_Z   = WSB_H1 + 2ull * 65536; // 2 KB zero emb row (fp32)
static constexpr size_t WSB_CTR = WSB_Z + 2048;          // 8 counters, 64B apart
static constexpr size_t WSB_EPO = WSB_CTR + 512;         // epoch flag, own line
static constexpr size_t WSB_FLG = WSB_EPO + 64;          // 256 init flags, 64B apart
static constexpr size_t WSB_END = WSB_FLG + 256 * 64;

static constexpr unsigned FMAGIC = 0x1357acedu;  // init-done flag value
static constexpr unsigned EPBASE = 0x40000000u;  // epoch base (post-init)
static constexpr int SPIN_CAP = 1 << 20;         // guard: fail fast, never hang

__device__ __forceinline__ unsigned ld_devu(const unsigned* p) {
    return __hip_atomic_load(p, __ATOMIC_RELAXED, __HIP_MEMORY_SCOPE_AGENT);
}
__device__ __forceinline__ unsigned long long ld_devu64(const unsigned long long* p) {
    return __hip_atomic_load(p, __ATOMIC_RELAXED, __HIP_MEMORY_SCOPE_AGENT);
}
__device__ __forceinline__ void st_devu(unsigned* p, unsigned v) {
    __hip_atomic_store(p, v, __ATOMIC_RELAXED, __HIP_MEMORY_SCOPE_AGENT);
}
template<int N> __device__ __forceinline__ void s_wait_vm() {
    asm volatile("s_waitcnt vmcnt(%0)" :: "n"(N) : "memory");
}
__device__ __forceinline__ void s_wait_lgkm() {
    asm volatile("s_waitcnt lgkmcnt(0)" ::: "memory");
}
__device__ __forceinline__ void wgbar() {
    asm volatile("" ::: "memory");
    __builtin_amdgcn_s_barrier();
    asm volatile("" ::: "memory");
}
__device__ __forceinline__ unsigned short bfc(float f) {
    __hip_bfloat16 h = __float2bfloat16(f);
    return *(unsigned short*)&h;
}
__device__ __forceinline__ float bf2f(unsigned short u) {
    __hip_bfloat16 h; *(unsigned short*)&h = u;
    return __bfloat162float(h);
}

// 16 cache-bypassing 16B loads of one slab row-slice (self-contained:
// internal vmcnt(0); outputs early-clobber so they can't alias the address
// operands while loads are in flight). Load i covers frag (c=i>>2, s=i&3):
// byte offset i*64 from (slab + voff).
__device__ __forceinline__ void ld_slab16(const char* slab, unsigned voff,
                                          bf16x8* f) {
    asm volatile(
        "global_load_dwordx4 %0, %16, %17 sc0 sc1\n\t"
        "global_load_dwordx4 %1, %16, %17 offset:64 sc0 sc1\n\t"
        "global_load_dwordx4 %2, %16, %17 offset:128 sc0 sc1\n\t"
        "global_load_dwordx4 %3, %16, %17 offset:192 sc0 sc1\n\t"
        "global_load_dwordx4 %4, %16, %17 offset:256 sc0 sc1\n\t"
        "global_load_dwordx4 %5, %16, %17 offset:320 sc0 sc1\n\t"
        "global_load_dwordx4 %6, %16, %17 offset:384 sc0 sc1\n\t"
        "global_load_dwordx4 %7, %16, %17 offset:448 sc0 sc1\n\t"
        "global_load_dwordx4 %8, %16, %17 offset:512 sc0 sc1\n\t"
        "global_load_dwordx4 %9, %16, %17 offset:576 sc0 sc1\n\t"
        "global_load_dwordx4 %10, %16, %17 offset:640 sc0 sc1\n\t"
        "global_load_dwordx4 %11, %16, %17 offset:704 sc0 sc1\n\t"
        "global_load_dwordx4 %12, %16, %17 offset:768 sc0 sc1\n\t"
        "global_load_dwordx4 %13, %16, %17 offset:832 sc0 sc1\n\t"
        "global_load_dwordx4 %14, %16, %17 offset:896 sc0 sc1\n\t"
        "global_load_dwordx4 %15, %16, %17 offset:960 sc0 sc1\n\t"
        "s_waitcnt vmcnt(0)"
        : "=&v"(f[0]), "=&v"(f[1]), "=&v"(f[2]), "=&v"(f[3]),
          "=&v"(f[4]), "=&v"(f[5]), "=&v"(f[6]), "=&v"(f[7]),
          "=&v"(f[8]), "=&v"(f[9]), "=&v"(f[10]), "=&v"(f[11]),
          "=&v"(f[12]), "=&v"(f[13]), "=&v"(f[14]), "=&v"(f[15])
        : "v"(voff), "s"(slab)
        : "memory");
}

__global__ __launch_bounds__(THR, 1)
void lstm_persistent(const int* __restrict__ xp,
                     const float* __restrict__ emb,
                     const float* __restrict__ W0,
                     const float* __restrict__ b0,
                     const float* __restrict__ W1,
                     const float* __restrict__ b1,
                     const float* __restrict__ fcw,
                     const float* __restrict__ fcb,
                     float* __restrict__ out,
                     float* __restrict__ ws)
{
    char* wsc = (char*)ws;

    unsigned* ctr = (unsigned*)(wsc + WSB_CTR);
    unsigned* epo = (unsigned*)(wsc + WSB_EPO);
    unsigned* flg = (unsigned*)(wsc + WSB_FLG);
    const float* zrow = (const float*)(wsc + WSB_Z);

    __shared__ float preF[16 * 68];   // gate preacts [w-row][batch], pad 68
    __shared__ float hexF[4 * 64];    // h exchange [h_local][batch]

    const int  tid   = threadIdx.x;
    const int  wg    = blockIdx.x;
    const bool is_l0 = (wg < 128);
    const int  hw    = (is_l0 ? wg : wg - 128) * 4;
    const float* Wb  = is_l0 ? W0 : W1;
    const float* bb  = is_l0 ? b0 : b1;
    const int  b_    = tid & 63;
    const int  wv    = __builtin_amdgcn_readfirstlane(tid >> 6);
    // MFMA lane decomposition (16x16x32): n = lane&15, q = lane>>4
    const int  n = tid & 15;
    const int  q = (tid & 63) >> 4;
    const int  b_row = wv * 16 + n;                       // this lane's batch row
    const unsigned rowB = (unsigned)(b_row * 1024 + q * 16); // byte off in slab

    // ---- diagnostic sentinel: proves launch (overwritten by real FC) ----
    if (wg == 0 && tid < 64) out[tid] = 0.25f;

    // ---- init: zero the 5 h slabs + the 2KB zero emb row ----
    {
        unsigned long long* hz = (unsigned long long*)(wsc + WSB_H0);
        for (int i = wg * THR + tid; i < 5 * 8192 + 256; i += NWGc * THR)
            __hip_atomic_store(hz + i, 0ull, __ATOMIC_RELAXED, __HIP_MEMORY_SCOPE_AGENT);
    }

    // ---- B-fragments: wave's 16 weight rows (w-row n), bf16, in VGPRs ----
    // frag f covers k in [f*32, f*32+32); lane holds k = f*32 + q*8 .. +8
    bf16x8 bw[32];
    {
        const float* wrow = Wb + (size_t)((n >> 2) * HIDc + hw + (n & 3)) * 1024;
        #pragma unroll
        for (int f = 0; f < 32; ++f) {
            const int k0 = f * 32 + q * 8;
            const float4 u0 = *(const float4*)(wrow + k0);
            const float4 u1 = *(const float4*)(wrow + k0 + 4);
            union { unsigned short us[8]; bf16x8 v; } pk;
            pk.us[0] = bfc(u0.x); pk.us[1] = bfc(u0.y);
            pk.us[2] = bfc(u0.z); pk.us[3] = bfc(u0.w);
            pk.us[4] = bfc(u1.x); pk.us[5] = bfc(u1.y);
            pk.us[6] = bfc(u1.z); pk.us[7] = bfc(u1.w);
            bw[f] = pk.v;
        }
    }
    const float bias_n = bb[(n >> 2) * HIDc + hw + (n & 3)];

    // ---- init barrier (round-8 verified; flags cleared at exit below) ----
    s_wait_vm<0>();
    wgbar();
    if (tid == 0) st_devu(&flg[wg * 16], FMAGIC);
    if (wg == 0 && tid == 0) {
        for (int g = 0; g < NWGc; ++g) {
            int gu = 0;
            while (ld_devu(&flg[g * 16]) != FMAGIC && ++gu < SPIN_CAP)
                __builtin_amdgcn_s_sleep(1);
        }
        #pragma unroll
        for (int g = 0; g < 8; ++g) st_devu(&ctr[g * 16], 0u);
        s_wait_vm<0>();
        st_devu(epo, EPBASE);
    } else if (tid == 0) {
        int gu = 0;
        while (ld_devu(epo) != EPBASE && ++gu < SPIN_CAP)
            __builtin_amdgcn_s_sleep(1);
    }
    wgbar();

    float cpriv = 0.0f;

    #pragma unroll 1
    for (int w = 0; w <= Tc + 1; ++w) {
        const bool a0  = is_l0 && (w < Tc);     // layer0 computes t=w
        const bool a1  = !is_l0 && (w >= 2);    // layer1 computes t=w-2
        const bool act = a0 || a1;

        f32x4 acc = {0.f, 0.f, 0.f, 0.f};

        // ---- pre-spin A-half: loads + 16 MFMAs ----
        if (a0) {
            // direct emb-table gather (immutable inputs -> cached loads)
            const int tok = xp[b_row * Tc + w];
            const float* er = tok ? (emb + (size_t)tok * 512) : zrow;
            #pragma unroll
            for (int c = 0; c < 4; ++c) {
                #pragma unroll
                for (int s = 0; s < 4; ++s) {
                    const int k0 = c * 128 + s * 32 + q * 8;
                    const float4 lo = *(const float4*)(er + k0);
                    const float4 hi = *(const float4*)(er + k0 + 4);
                    union { unsigned short us[8]; bf16x8 v; } pk;
                    pk.us[0] = bfc(lo.x); pk.us[1] = bfc(lo.y);
                    pk.us[2] = bfc(lo.z); pk.us[3] = bfc(lo.w);
                    pk.us[4] = bfc(hi.x); pk.us[5] = bfc(hi.y);
                    pk.us[6] = bfc(hi.z); pk.us[7] = bfc(hi.w);
                    acc = __builtin_amdgcn_mfma_f32_16x16x32_bf16(
                        pk.v, bw[c * 4 + s], acc, 0, 0, 0);
                }
            }
        } else if (a1) {
            // h0(w-2): ready since gate w-1 (previous iteration)
            bf16x8 fa[16];
            ld_slab16(wsc + WSB_H0 + (size_t)((w - 2) % 3) * 65536, rowB, fa);
            #pragma unroll
            for (int i = 0; i < 16; ++i)
                acc = __builtin_amdgcn_mfma_f32_16x16x32_bf16(fa[i], bw[i], acc, 0, 0, 0);
        }

        // ---- leader/epoch barrier w (round-8 verified, byte-identical) ----
        if (wg == 0) {
            if (tid == 0) {
                const unsigned tgt = (unsigned)NWGc * (unsigned)w;
                int gu = 0;
                for (;;) {
                    unsigned s = 0;
                    #pragma unroll
                    for (int g = 0; g < 8; ++g) s += ld_devu(&ctr[g * 16]);
                    if (s >= tgt || ++gu >= SPIN_CAP) break;
                }
                st_devu(epo, EPBASE + 1u + (unsigned)w);
            }
        } else {
            if (tid == 0) {
                int gu = 0;
                while (ld_devu(epo) < EPBASE + 1u + (unsigned)w && ++gu < SPIN_CAP)
                    __builtin_amdgcn_s_sleep(1);
            }
        }
        wgbar();

        if (act) {
            // ---- B-half: recurrent slab, 16B sc0/sc1 loads + 16 MFMAs ----
            const char* slabB = is_l0
                ? (wsc + WSB_H0 + (size_t)((w + 2) % 3) * 65536)      // h0(w-1)
                : (wsc + WSB_H1 + (size_t)((w - 3) & 1) * 65536);     // h1(w-3)
            bf16x8 fb[16];
            ld_slab16(slabB, rowB, fb);
            #pragma unroll
            for (int i = 0; i < 16; ++i)
                acc = __builtin_amdgcn_mfma_f32_16x16x32_bf16(fb[i], bw[16 + i], acc, 0, 0, 0);

            // ---- gate exchange: lane reg r holds D[batch q*4+r][w-row n] ----
            *(f32x4*)(preF + (size_t)n * 68 + wv * 16 + q * 4) = acc + bias_n;
            s_wait_lgkm(); wgbar();

            // cell update: thread (b_, h_local = wv); gate g at w-row g*4+wv
            const float pI = preF[(0 * 4 + wv) * 68 + b_];
            const float pF = preF[(1 * 4 + wv) * 68 + b_];
            const float pO = preF[(2 * 4 + wv) * 68 + b_];
            const float pG = preF[(3 * 4 + wv) * 68 + b_];
            const float ig = 1.f / (1.f + expf(-pI));
            const float fg = 1.f / (1.f + expf(-pF));
            const float og = 1.f / (1.f + expf(-pO));
            const float gg = fmaxf(pG, 0.f);
            cpriv = fg * cpriv + ig * gg;
            const float hn = og * fmaxf(cpriv, 0.f);
            hexF[wv * 64 + b_] = hn;
            s_wait_lgkm(); wgbar();

            // h-write: wave 0 packs 4 bf16 -> one 8 B store per batch row
            if (tid < 64) {
                unsigned long long pk = 0;
                #pragma unroll
                for (int jj = 0; jj < 4; ++jj)
                    pk |= (unsigned long long)bfc(hexF[jj * 64 + tid]) << (16 * jj);
                unsigned short* hdst = is_l0
                    ? (unsigned short*)(wsc + WSB_H0 + (size_t)(w % 3) * 65536)
                    : (unsigned short*)(wsc + WSB_H1 + (size_t)((w - 2) & 1) * 65536);
                __hip_atomic_store((unsigned long long*)(hdst + (size_t)tid * 512 + hw),
                                   pk, __ATOMIC_RELAXED, __HIP_MEMORY_SCOPE_AGENT);
            }
        }

        // ---- arrive for barrier w+1 ----
        s_wait_vm<0>();   // h-store acked at coherent point
        wgbar();
        if (tid == 0)
            __hip_atomic_fetch_add(&ctr[(wg & 7) * 16], 1u, __ATOMIC_RELAXED,
                                   __HIP_MEMORY_SCOPE_AGENT);
    }

    // ---- clear own init flag (replay-race hardening) ----
    if (tid == 0) st_devu(&flg[wg * 16], 0u);

    // ---- final FC + sigmoid on h1(Tc-1) ----
    if (wg == 0) {
        if (tid == 0) {
            const unsigned tgt = (unsigned)NWGc * (unsigned)(Tc + 2);
            int gu = 0;
            for (;;) {
                unsigned s = 0;
                #pragma unroll
                for (int g = 0; g < 8; ++g) s += ld_devu(&ctr[g * 16]);
                if (s >= tgt || ++gu >= SPIN_CAP) break;
            }
        }
        wgbar();
        if (tid < 64) {
            const unsigned short* h1f =
                (const unsigned short*)(wsc + WSB_H1 + (size_t)((Tc - 1) & 1) * 65536)
                + (size_t)tid * 512;
            float s = fcb[0];
            for (int h = 0; h < HIDc; h += 4) {
                const unsigned long long u = ld_devu64((const unsigned long long*)(h1f + h));
                s = fmaf(bf2f((unsigned short)(u        & 0xffff)), fcw[h + 0], s);
                s = fmaf(bf2f((unsigned short)((u >> 16) & 0xffff)), fcw[h + 1], s);
                s = fmaf(bf2f((unsigned short)((u >> 32) & 0xffff)), fcw[h + 2], s);
                s = fmaf(bf2f((unsigned short)((u >> 48) & 0xffff)), fcw[h + 3], s);
            }
            out[tid] = 1.f / (1.f + expf(-s));
        }
    }
}

extern "C" void kernel_launch(void* const* d_in, const int* in_sizes, int n_in,
                              void* d_out, int out_size, void* d_ws, size_t ws_size,
                              hipStream_t stream) {
    const int*   xp  = (const int*)d_in[0];
    const float* emb = (const float*)d_in[1];
    const float* W0  = (const float*)d_in[2];
    const float* b0  = (const float*)d_in[3];
    const float* W1  = (const float*)d_in[4];
    const float* b1  = (const float*)d_in[5];
    const float* fcw = (const float*)d_in[6];
    const float* fcb = (const float*)d_in[7];
    float* out = (float*)d_out;
    float* ws  = (float*)d_ws;

    if (ws_size < WSB_END) return;  // loud fail: out stays poisoned

    // Plain launch: 256 WGs x 256 thr, 1 WG/CU on 256 CUs -> co-resident.
    lstm_persistent<<<dim3(NWGc), dim3(THR), 0, stream>>>(
        xp, emb, W0, b0, W1, b1, fcw, fcb, out, ws);
}